// Round 12
// baseline (136.609 us; speedup 1.0000x reference)
//
#include <hip/hip_runtime.h>
#include <stdint.h>

#define HW_  16384
#define CH   256
#define NB   8
#define NTI  256          // 64-wide n-tiles per batch
#define EPSV 1e-5f

typedef float f32x4 __attribute__((ext_vector_type(4)));
typedef short s16x8 __attribute__((ext_vector_type(8)));

__device__ __forceinline__ unsigned short f2bf(float f) {
    union { float f; uint32_t u; } v; v.f = f;
    uint32_t r = (v.u + 0x7FFFu + ((v.u >> 16) & 1u)) >> 16;  // RNE
    return (unsigned short)r;
}

// async global -> LDS. Global source address is PER-LANE; LDS dest is
// wave-uniform base + lane*16B (HW-appended).  [m104/m108]
__device__ __forceinline__ void glds16(const unsigned short* g, unsigned short* l) {
    __builtin_amdgcn_global_load_lds(
        (const __attribute__((address_space(1))) uint32_t*)g,
        (__attribute__((address_space(3))) uint32_t*)l,
        16, 0, 0);
}

// ---------------------------------------------------------------------------
// K0: fused stats + transpose-to-bf16.  Block = (ntile64 bx, batch b), 256thr.
// Reads x[b][0..255][n0..n0+63]; emits per-(b,c) partials for this tile and
// the xT tile in the gemm's exact DMA order: [b][bx][kb][g][n][8] bf16.
// LDS: [128 cp][64+2 pad] u32 (33KB) -> 4 blocks/CU.
// ---------------------------------------------------------------------------
__global__ __launch_bounds__(256) void tstat_kernel(const float* __restrict__ x,
                                                    unsigned short* __restrict__ xT,
                                                    float* __restrict__ partS,
                                                    float* __restrict__ partQ) {
    const int b  = blockIdx.y;
    const int bx = blockIdx.x;
    const int n0 = bx * 64;
    const int t  = threadIdx.x;

    __shared__ uint32_t T2[128 * 66];   // [cp][n+2 pad]; u32 = bf16(2cp)|bf16(2cp+1)<<16

    const float* xb = x + (size_t)b * CH * HW_ + n0;
    const int l16 = t & 15;             // n-quad lane
    const int cg  = t >> 4;             // c-pair group 0..15
    const int n4  = l16 * 4;

    // phase 1: 8 passes x (2 rows/thread); stats + packed LDS write
#pragma unroll 2
    for (int p = 0; p < 8; ++p) {
        const int cp = p * 16 + cg;          // c-pair 0..127
        const float* pa = xb + (size_t)(2 * cp) * HW_ + n4;
        f32x4 va = *reinterpret_cast<const f32x4*>(pa);
        f32x4 vb = *reinterpret_cast<const f32x4*>(pa + HW_);

        float sA = va[0] + va[1] + va[2] + va[3];
        float qA = va[0]*va[0] + va[1]*va[1] + va[2]*va[2] + va[3]*va[3];
        float sB = vb[0] + vb[1] + vb[2] + vb[3];
        float qB = vb[0]*vb[0] + vb[1]*vb[1] + vb[2]*vb[2] + vb[3]*vb[3];
#pragma unroll
        for (int off = 1; off < 16; off <<= 1) {
            sA += __shfl_xor(sA, off, 16);
            qA += __shfl_xor(qA, off, 16);
            sB += __shfl_xor(sB, off, 16);
            qB += __shfl_xor(qB, off, 16);
        }
        if (l16 == 0) {
            partS[(size_t)(b * CH + 2 * cp    ) * NTI + bx] = sA;
            partQ[(size_t)(b * CH + 2 * cp    ) * NTI + bx] = qA;
            partS[(size_t)(b * CH + 2 * cp + 1) * NTI + bx] = sB;
            partQ[(size_t)(b * CH + 2 * cp + 1) * NTI + bx] = qB;
        }
#pragma unroll
        for (int j = 0; j < 4; ++j)
            T2[cp * 66 + n4 + j] =
                (uint32_t)f2bf(va[j]) | ((uint32_t)f2bf(vb[j]) << 16);
    }
    __syncthreads();

    // phase 2: emit 2048 x 16B entries [kb][g][n][8c]; reads are column u32s
    // (bank = (2cp+n)%32, lanes vary n -> 2 lanes/bank, free); stores 1KB/wave.
    uint4* dst = reinterpret_cast<uint4*>(xT + ((size_t)(b * NTI + bx)) * 16384);
#pragma unroll 2
    for (int it = 0; it < 8; ++it) {
        const int idx = it * 256 + t;     // kb*256 + g*64 + n
        const int n   = idx & 63;
        const int cp0 = (idx >> 6) * 4;   // (kb*16 + g*4)
        uint4 o;
        o.x = T2[(cp0 + 0) * 66 + n];
        o.y = T2[(cp0 + 1) * 66 + n];
        o.z = T2[(cp0 + 2) * 66 + n];
        o.w = T2[(cp0 + 3) * 66 + n];
        dst[idx] = o;
    }
}

// ---------------------------------------------------------------------------
// K2: reduce partials, finalize stats, fold A' (pre-tiled Atile[b][kb][g][m][8])
// + bias D'.
// ---------------------------------------------------------------------------
__global__ __launch_bounds__(256) void prep_kernel(const float* __restrict__ partS,
                                                   const float* __restrict__ partQ,
                                                   const float* __restrict__ params,
                                                   const float* __restrict__ W,
                                                   unsigned short* __restrict__ Atile,
                                                   float* __restrict__ Dp) {
    const int b   = blockIdx.x;
    const int tid = threadIdx.x;
    __shared__ float mu[CH], ri[CH], rs[CH], rq[CH];

    float s = 0.f, q = 0.f;
    const f32x4* ps = reinterpret_cast<const f32x4*>(partS + (size_t)(b * CH + tid) * NTI);
    const f32x4* pq = reinterpret_cast<const f32x4*>(partQ + (size_t)(b * CH + tid) * NTI);
#pragma unroll 8
    for (int i = 0; i < NTI / 4; ++i) {
        f32x4 a = ps[i], c4 = pq[i];
        s += a[0] + a[1] + a[2] + a[3];
        q += c4[0] + c4[1] + c4[2] + c4[3];
    }

    float m = s * (1.0f / HW_);
    float v = q * (1.0f / HW_) - m * m;
    mu[tid] = m;
    ri[tid] = rsqrtf(v + EPSV);
    rs[tid] = s; rq[tid] = q;
    __syncthreads();
    for (int off = 128; off > 0; off >>= 1) {
        if (tid < off) { rs[tid] += rs[tid + off]; rq[tid] += rq[tid + off]; }
        __syncthreads();
    }
    const float invN = 1.0f / ((float)CH * (float)HW_);
    const float mln  = rs[0] * invN;
    const float vln  = rq[0] * invN - mln * mln;
    const float rln  = rsqrtf(vln + EPSV);

    const int o = tid;
    const float gamma = params[b * 2 * CH + o];
    const float beta  = params[b * 2 * CH + CH + o];
    const float4* w1p = reinterpret_cast<const float4*>(W + (size_t)o * 2 * CH);
    const float4* w2p = reinterpret_cast<const float4*>(W + (size_t)o * 2 * CH + CH);
    unsigned short* ab = Atile + (size_t)b * (8 * 4 * 256 * 8);
    float t1 = 0.f, t2 = 0.f;
    for (int c4i = 0; c4i < CH / 4; ++c4i) {
        float4 w1 = w1p[c4i];
        float4 w2 = w2p[c4i];
        float w1a[4] = {w1.x, w1.y, w1.z, w1.w};
        float w2a[4] = {w2.x, w2.y, w2.z, w2.w};
        const int c = c4i * 4;
        ushort4 pk;
        unsigned short* pka = (unsigned short*)&pk;
#pragma unroll
        for (int j = 0; j < 4; ++j) {
            float ric = ri[c + j];
            float a   = gamma * (w1a[j] * ric + w2a[j] * rln);
            pka[j] = f2bf(a);
            t1 += w1a[j] * ric * mu[c + j];
            t2 += w2a[j];
        }
        const int kb = c >> 5, g = (c >> 3) & 3, e0 = c & 4;
        *reinterpret_cast<ushort4*>(&ab[(size_t)(((kb * 4 + g) * 256 + o) * 8 + e0)]) = pk;
    }
    const float d = -(t1 + rln * mln * t2);
    Dp[b * CH + o] = gamma * d + beta;
}

// ---------------------------------------------------------------------------
// K3: batched MFMA GEMM, 100%-DMA staging (both operands pre-tiled in memory).
// out[b][m][n] = sum_c A'[b][m][c] * x[b][c][n] + D'
// BM=256, BN=128, BK=32. 512 thr = 8 waves, wave 64x64 (4x4 frags 16x16x32).
// Per K-step: syncthreads -> 3 glds16/wave (As kb+1 x2, Xs kb+1 x1) ->
// ds_read + MFMA. No in-loop VALU, no ds_writes, ~100 VGPR (no spill).
// ---------------------------------------------------------------------------
__global__ __launch_bounds__(512, 4) void gemm_kernel(const unsigned short* __restrict__ xT,
                                                      const unsigned short* __restrict__ Atile,
                                                      const float* __restrict__ Dp,
                                                      float* __restrict__ out) {
    __shared__ unsigned short As[2][4 * 256 * 8];  // [buf][g][m][8]       16 KB
    __shared__ unsigned short Xs[2][4 * 2 * 64 * 8]; // [buf][g][half][n][8] 8 KB

    const int b   = blockIdx.y;
    const int bx  = blockIdx.x;          // 128-wide n-tile
    const int n0  = bx * 128;
    const int t   = threadIdx.x;
    const int w   = t >> 6;
    const int l   = t & 63;
    const int wm  = w >> 1;        // 0..3
    const int wn  = w & 1;         // 0..1
    const int lhi = l >> 4;        // 0..3 (k-group)
    const int llo = l & 15;

    // acc init = bias D' (MFMA C-operand)
    f32x4 acc[4][4];
    const float* dpb = Dp + b * CH;
#pragma unroll
    for (int fm = 0; fm < 4; ++fm) {
        f32x4 d = *reinterpret_cast<const f32x4*>(dpb + wm * 64 + fm * 16 + lhi * 4);
#pragma unroll
        for (int fn = 0; fn < 4; ++fn) acc[fm][fn] = d;
    }

    const unsigned short* apb = Atile + (size_t)b * (8 * 4 * 256 * 8);

    // ---- As DMA: wave w issues i=2w,2w+1 -> (g=i&3, q=i>>2); per-lane +l*8
    const int i0 = 2 * w,      i1 = 2 * w + 1;
    const int g0 = i0 & 3,     q0 = i0 >> 2;
    const int g1 = i1 & 3,     q1 = i1 >> 2;
    const unsigned short* aglob0 = apb + (size_t)(g0 * 256 + q0 * 64 + l) * 8;
    const unsigned short* aglob1 = apb + (size_t)(g1 * 256 + q1 * 64 + l) * 8;
    unsigned short* alds0 = &As[0][g0 * 2048 + q0 * 512];
    unsigned short* alds1 = &As[0][g1 * 2048 + q1 * 512];

    // ---- Xs DMA: wave w -> (g = w>>1, half = w&1); 64n x 16B per instr
    const int xg = w >> 1, xh = w & 1;
    const unsigned short* xglob =
        xT + ((size_t)(b * NTI + 2 * bx + xh)) * 16384 + (size_t)(xg * 64 + l) * 8;
    unsigned short* xlds = &Xs[0][(xg * 2 + xh) * 512];

    // prologue: DMA tile 0
    glds16(aglob0, alds0);
    glds16(aglob1, alds1);
    glds16(xglob,  xlds);

#pragma unroll
    for (int kb = 0; kb < 8; ++kb) {
        __syncthreads();   // drains DMA(kb); ends compute(kb-1)
        const int cur = kb & 1, nxt = cur ^ 1;

        if (kb < 7) {
            glds16(aglob0 + (kb + 1) * 8192, alds0 + nxt * 8192);
            glds16(aglob1 + (kb + 1) * 8192, alds1 + nxt * 8192);
            glds16(xglob  + (kb + 1) * 2048, xlds  + nxt * 4096);
        }

        // compute(kb)
        s16x8 af[4];
#pragma unroll
        for (int fm = 0; fm < 4; ++fm)
            af[fm] = *reinterpret_cast<const s16x8*>(&As[cur][lhi * 2048 + (wm * 64 + fm * 16 + llo) * 8]);
#pragma unroll
        for (int fn = 0; fn < 4; ++fn) {
            s16x8 bfr = *reinterpret_cast<const s16x8*>(
                &Xs[cur][(lhi * 2 + wn) * 512 + (fn * 16 + llo) * 8]);
#pragma unroll
            for (int fm = 0; fm < 4; ++fm)
                acc[fm][fn] = __builtin_amdgcn_mfma_f32_16x16x32_bf16(af[fm], bfr, acc[fm][fn], 0, 0, 0);
        }
    }

    // epilogue (plain stores; NT regressed in R11)
#pragma unroll
    for (int fm = 0; fm < 4; ++fm) {
        const int m = wm * 64 + fm * 16 + lhi * 4;
        float* obase = out + (size_t)(b * CH + m) * HW_ + n0 + wn * 64 + llo;
#pragma unroll
        for (int fn = 0; fn < 4; ++fn) {
#pragma unroll
            for (int r = 0; r < 4; ++r)
                obase[(size_t)r * HW_ + fn * 16] = acc[fm][fn][r];
        }
    }
}

// ---------------------------------------------------------------------------
extern "C" void kernel_launch(void* const* d_in, const int* in_sizes, int n_in,
                              void* d_out, int out_size, void* d_ws, size_t ws_size,
                              hipStream_t stream) {
    const float* x      = (const float*)d_in[0];
    const float* params = (const float*)d_in[1];
    const float* W      = (const float*)d_in[2];
    float* out = (float*)d_out;
    char*  ws  = (char*)d_ws;

    float*          partS = (float*)(ws);                       // 2 MB
    float*          partQ = (float*)(ws + (2u << 20));          // 2 MB
    float*          Dp    = (float*)(ws + (4u << 20));          // 8 KB
    unsigned short* Atile = (unsigned short*)(ws + (5u << 20)); // 1 MB
    unsigned short* xT    = (unsigned short*)(ws + (8u << 20)); // 64 MB

    hipLaunchKernelGGL(tstat_kernel, dim3(NTI, NB), dim3(256), 0, stream, x, xT, partS, partQ);
    hipLaunchKernelGGL(prep_kernel,  dim3(NB),      dim3(256), 0, stream, partS, partQ, params, W, Atile, Dp);
    hipLaunchKernelGGL(gemm_kernel,  dim3(HW_ / 128, NB), dim3(512), 0, stream, xT, Atile, Dp, out);
}

// Round 13
// 110.138 us; speedup vs baseline: 1.2403x; 1.2403x over previous
//
#include <hip/hip_runtime.h>
#include <hip/hip_bf16.h>
#include <stdint.h>

#define HW_  16384
#define CH   256
#define NB   8
#define EPSV 1e-5f

typedef float f32x4 __attribute__((ext_vector_type(4)));
typedef short s16x8 __attribute__((ext_vector_type(8)));
typedef uint32_t u32x4 __attribute__((ext_vector_type(4)));

__device__ __forceinline__ unsigned short f2bf(float f) {
    union { float f; uint32_t u; } v; v.f = f;
    uint32_t r = (v.u + 0x7FFFu + ((v.u >> 16) & 1u)) >> 16;  // RNE
    return (unsigned short)r;
}

// pack two floats -> u32 of two bf16 (RNE); compiler emits v_cvt_pk_bf16_f32
__device__ __forceinline__ uint32_t pkbf(float lo, float hi) {
    __hip_bfloat162 h = __float22bfloat162_rn(make_float2(lo, hi));
    union { __hip_bfloat162 h; uint32_t u; } v; v.h = h;
    return v.u;
}

// async global -> LDS. Global source address is PER-LANE; LDS dest is
// wave-uniform base + lane*16B (HW-appended).  [m104/m108]
__device__ __forceinline__ void glds16(const unsigned short* g, unsigned short* l) {
    __builtin_amdgcn_global_load_lds(
        (const __attribute__((address_space(1))) uint32_t*)g,
        (__attribute__((address_space(3))) uint32_t*)l,
        16, 0, 0);
}

// ---------------------------------------------------------------------------
// K1: stats + bf16 pair-pack.  Block = c-pair (1024 blocks x 256 thr).
// Reads rows 2cp, 2cp+1 of x; writes xp[bcp][n] = bf16(row2cp)|bf16(row2cp+1)<<16
// (the exact u32 the gemm's Xs staging needs) + per-row sums/sumsq.
// ---------------------------------------------------------------------------
__global__ __launch_bounds__(256) void pack_kernel(const float* __restrict__ x,
                                                   uint32_t* __restrict__ xp,
                                                   float* __restrict__ sums,
                                                   float* __restrict__ sumsq) {
    const int bcp = blockIdx.x;          // b*128 + cp
    const int tid = threadIdx.x;
    const f32x4* pa = reinterpret_cast<const f32x4*>(x + (size_t)(2 * bcp) * HW_);
    const f32x4* pb = reinterpret_cast<const f32x4*>(x + (size_t)(2 * bcp + 1) * HW_);
    u32x4* dst = reinterpret_cast<u32x4*>(xp + (size_t)bcp * HW_);

    float sA = 0.f, qA = 0.f, sB = 0.f, qB = 0.f;
#pragma unroll 4
    for (int i = tid; i < HW_ / 4; i += 256) {
        f32x4 va = pa[i], vb = pb[i];
        sA += va[0] + va[1] + va[2] + va[3];
        qA += va[0]*va[0] + va[1]*va[1] + va[2]*va[2] + va[3]*va[3];
        sB += vb[0] + vb[1] + vb[2] + vb[3];
        qB += vb[0]*vb[0] + vb[1]*vb[1] + vb[2]*vb[2] + vb[3]*vb[3];
        u32x4 o;
        o[0] = pkbf(va[0], vb[0]);
        o[1] = pkbf(va[1], vb[1]);
        o[2] = pkbf(va[2], vb[2]);
        o[3] = pkbf(va[3], vb[3]);
        dst[i] = o;
    }
    __shared__ float r0[256], r1[256], r2[256], r3[256];
    r0[tid] = sA; r1[tid] = qA; r2[tid] = sB; r3[tid] = qB;
    __syncthreads();
    for (int off = 128; off > 0; off >>= 1) {
        if (tid < off) {
            r0[tid] += r0[tid + off]; r1[tid] += r1[tid + off];
            r2[tid] += r2[tid + off]; r3[tid] += r3[tid + off];
        }
        __syncthreads();
    }
    if (tid == 0) {
        sums [2 * bcp    ] = r0[0];
        sumsq[2 * bcp    ] = r1[0];
        sums [2 * bcp + 1] = r2[0];
        sumsq[2 * bcp + 1] = r3[0];
    }
}

// ---------------------------------------------------------------------------
// K2: finalize stats, fold into A' + D'. A' written PRE-TILED in the gemm's
// LDS order: Atile[b][kb][g][m][8]  (kb = K-tile, g = k-octet, m = o).
// ---------------------------------------------------------------------------
__global__ __launch_bounds__(256) void prep_kernel(const float* __restrict__ sums,
                                                   const float* __restrict__ sumsq,
                                                   const float* __restrict__ params,
                                                   const float* __restrict__ W,
                                                   unsigned short* __restrict__ Atile,
                                                   float* __restrict__ Dp) {
    const int b   = blockIdx.x;
    const int tid = threadIdx.x;
    __shared__ float mu[CH], ri[CH], rs[CH], rq[CH];
    float s = sums[b * CH + tid];
    float q = sumsq[b * CH + tid];
    float m = s * (1.0f / HW_);
    float v = q * (1.0f / HW_) - m * m;
    mu[tid] = m;
    ri[tid] = rsqrtf(v + EPSV);
    rs[tid] = s; rq[tid] = q;
    __syncthreads();
    for (int off = 128; off > 0; off >>= 1) {
        if (tid < off) { rs[tid] += rs[tid + off]; rq[tid] += rq[tid + off]; }
        __syncthreads();
    }
    const float invN = 1.0f / ((float)CH * (float)HW_);
    const float mln  = rs[0] * invN;
    const float vln  = rq[0] * invN - mln * mln;
    const float rln  = rsqrtf(vln + EPSV);

    const int o = tid;
    const float gamma = params[b * 2 * CH + o];
    const float beta  = params[b * 2 * CH + CH + o];
    const float4* w1p = reinterpret_cast<const float4*>(W + (size_t)o * 2 * CH);
    const float4* w2p = reinterpret_cast<const float4*>(W + (size_t)o * 2 * CH + CH);
    unsigned short* ab = Atile + (size_t)b * (8 * 4 * 256 * 8);
    float t1 = 0.f, t2 = 0.f;
    for (int c4 = 0; c4 < CH / 4; ++c4) {
        float4 w1 = w1p[c4];
        float4 w2 = w2p[c4];
        float w1a[4] = {w1.x, w1.y, w1.z, w1.w};
        float w2a[4] = {w2.x, w2.y, w2.z, w2.w};
        const int c = c4 * 4;
        ushort4 pk;
        unsigned short* pka = (unsigned short*)&pk;
#pragma unroll
        for (int j = 0; j < 4; ++j) {
            float ric = ri[c + j];
            float a   = gamma * (w1a[j] * ric + w2a[j] * rln);
            pka[j] = f2bf(a);
            t1 += w1a[j] * ric * mu[c + j];
            t2 += w2a[j];
        }
        const int kb = c >> 5, g = (c >> 3) & 3, e0 = c & 4;
        *reinterpret_cast<ushort4*>(&ab[(size_t)(((kb * 4 + g) * 256 + o) * 8 + e0)]) = pk;
    }
    const float d = -(t1 + rln * mln * t2);
    Dp[b * CH + o] = gamma * d + beta;
}

// ---------------------------------------------------------------------------
// K3: batched MFMA GEMM (R10 schedule; x staged from pre-packed bf16 xp).
// out[b][m][n] = sum_c A'[b][m][c] * x[b][c][n] + D'
// BM=256, BN=128, BK=32. 512 thr = 8 waves, wave 64x64 (4x4 frags 16x16x32).
// Per K-step: [vmcnt(2) lgkmcnt(0); barrier] -> DMA As(kb+1) -> load xp(kb+2)
// (ONE uint4/thread) -> compute(kb) -> 4x ds_write_b32 Xs(kb+1). No in-loop
// conversion VALU; ~95 live VGPRs.
// ---------------------------------------------------------------------------
__global__ __launch_bounds__(512, 4) void gemm_kernel(const uint32_t* __restrict__ xp,
                                                      const unsigned short* __restrict__ Atile,
                                                      const float* __restrict__ Dp,
                                                      float* __restrict__ out) {
    __shared__ unsigned short As[2][4 * 256 * 8];  // [buf][g][m][8]   16 KB each
    __shared__ unsigned short Xs[2][4 * 128 * 8];  // [buf][g][n_p][8]  8 KB each

    const int b   = blockIdx.y;
    const int n0  = blockIdx.x * 128;
    const int t   = threadIdx.x;
    const int w   = t >> 6;
    const int l   = t & 63;
    const int wm  = w >> 1;        // 0..3
    const int wn  = w & 1;         // 0..1
    const int lhi = l >> 4;        // 0..3 (k-group)
    const int llo = l & 15;

    // acc init = bias D' (MFMA C-operand)
    f32x4 acc[4][4];
    const float* dpb = Dp + b * CH;
#pragma unroll
    for (int fm = 0; fm < 4; ++fm) {
        f32x4 d = *reinterpret_cast<const f32x4*>(dpb + wm * 64 + fm * 16 + lhi * 4);
#pragma unroll
        for (int fn = 0; fn < 4; ++fn) acc[fm][fn] = d;
    }

    const unsigned short* apb = Atile + (size_t)b * (8 * 4 * 256 * 8);
    uint32_t* Xs32 = reinterpret_cast<uint32_t*>(&Xs[0][0]);

    // ---- As DMA mapping: wave w issues instrs i=2w,2w+1; i -> (g=i&3, q=i>>2)
    const int i0 = 2 * w,      i1 = 2 * w + 1;
    const int g0 = i0 & 3,     q0 = i0 >> 2;
    const int g1 = i1 & 3,     q1 = i1 >> 2;
    const unsigned short* aglob0 = apb + (size_t)(g0 * 256 + q0 * 64 + l) * 8;
    const unsigned short* aglob1 = apb + (size_t)(g1 * 256 + q1 * 64 + l) * 8;
    unsigned short* alds0 = &As[0][g0 * 2048 + q0 * 512];  // + l*16B by HW
    unsigned short* alds1 = &As[0][g1 * 2048 + q1 * 512];

    // ---- Xs staging mapping: thread -> c-pair row kp, n-quad nq
    const int kp = t >> 5;              // k-pair 0..15 within K-tile
    const int nq = t & 31;              // n-quad (half-wave = 512B row segment)
    const int xg = kp >> 2;             // Xs g
    const int xh = kp & 3;              // u32 slot within octet
    // xp row index for K-tile kb: b*128 + kb*16 + kp
    const uint32_t* xlane = xp + (size_t)(b * 128 + kp) * HW_ + n0 + nq * 4;

    // read-side swizzled n per fn
    int npr[4];
#pragma unroll
    for (int fn = 0; fn < 4; ++fn) {
        const int nr = wn * 64 + fn * 16 + llo;
        npr[fn] = nr ^ ((nr >> 3) & 7);
    }

    // ---- prologue: DMA As(0), load xp tiles 0 and 1, stage Xs[0]
    glds16(aglob0, alds0);
    glds16(aglob1, alds1);
    u32x4 xv[2];
    xv[0] = *reinterpret_cast<const u32x4*>(xlane);
    xv[1] = *reinterpret_cast<const u32x4*>(xlane + (size_t)16 * HW_);
#pragma unroll
    for (int j = 0; j < 4; ++j) {
        const int n  = nq * 4 + j;
        const int np = n ^ ((n >> 3) & 7);
        Xs32[xg * 512 + np * 4 + xh] = xv[0][j];
    }

#pragma unroll
    for (int kb = 0; kb < 8; ++kb) {
        const int cur = kb & 1, nxt = cur ^ 1;

        // counted-vmcnt barrier: As(kb) DMA drained; newest 2... (1 uint4 + 1
        // possible straggler) xp prefetches may stay in flight.
        if (kb == 7) {
            asm volatile("s_waitcnt vmcnt(0) lgkmcnt(0)" ::: "memory");
        } else {
            asm volatile("s_waitcnt vmcnt(1) lgkmcnt(0)" ::: "memory");
        }
        __builtin_amdgcn_s_barrier();

        if (kb < 7) {
            // DMA As(kb+1): lane-consecutive 16B -> 1KB coalesced per instr
            glds16(aglob0 + (kb + 1) * 8192, alds0 + nxt * 8192);
            glds16(aglob1 + (kb + 1) * 8192, alds1 + nxt * 8192);
        }
        if (kb < 6) {
            xv[cur] = *reinterpret_cast<const u32x4*>(xlane + (size_t)(kb + 2) * 16 * HW_);
        }

        // compute(kb) from cur buffers
        s16x8 af[4];
#pragma unroll
        for (int fm = 0; fm < 4; ++fm)
            af[fm] = *reinterpret_cast<const s16x8*>(&As[cur][lhi * 2048 + (wm * 64 + fm * 16 + llo) * 8]);
#pragma unroll
        for (int fn = 0; fn < 4; ++fn) {
            s16x8 bfr = *reinterpret_cast<const s16x8*>(&Xs[cur][lhi * 1024 + npr[fn] * 8]);
#pragma unroll
            for (int fm = 0; fm < 4; ++fm)
                acc[fm][fn] = __builtin_amdgcn_mfma_f32_16x16x32_bf16(af[fm], bfr, acc[fm][fn], 0, 0, 0);
        }

        // stage Xs(kb+1) AFTER compute from regs loaded one phase earlier
        if (kb < 7) {
#pragma unroll
            for (int j = 0; j < 4; ++j) {
                const int n  = nq * 4 + j;
                const int np = n ^ ((n >> 3) & 7);
                Xs32[nxt * 2048 + xg * 512 + np * 4 + xh] = xv[nxt][j];
            }
        }
    }

    // epilogue: bias already folded into acc (plain stores; NT regressed R11)
#pragma unroll
    for (int fm = 0; fm < 4; ++fm) {
        const int m = wm * 64 + fm * 16 + lhi * 4;
        float* obase = out + (size_t)(b * CH + m) * HW_ + n0 + wn * 64 + llo;
#pragma unroll
        for (int fn = 0; fn < 4; ++fn) {
#pragma unroll
            for (int r = 0; r < 4; ++r)
                obase[(size_t)r * HW_ + fn * 16] = acc[fm][fn][r];
        }
    }
}

// ---------------------------------------------------------------------------
extern "C" void kernel_launch(void* const* d_in, const int* in_sizes, int n_in,
                              void* d_out, int out_size, void* d_ws, size_t ws_size,
                              hipStream_t stream) {
    const float* x      = (const float*)d_in[0];
    const float* params = (const float*)d_in[1];
    const float* W      = (const float*)d_in[2];
    float* out = (float*)d_out;
    char*  ws  = (char*)d_ws;

    float*          sums  = (float*)(ws);                       // 8 KB
    float*          sumsq = (float*)(ws + (1u << 20));          // 8 KB
    float*          Dp    = (float*)(ws + (2u << 20));          // 8 KB
    unsigned short* Atile = (unsigned short*)(ws + (3u << 20)); // 1 MB
    uint32_t*       xp    = (uint32_t*)(ws + (8u << 20));       // 64 MB

    hipLaunchKernelGGL(pack_kernel, dim3(NB * 128), dim3(256), 0, stream, x, xp, sums, sumsq);
    hipLaunchKernelGGL(prep_kernel, dim3(NB),       dim3(256), 0, stream, sums, sumsq, params, W, Atile, Dp);
    hipLaunchKernelGGL(gemm_kernel, dim3(HW_ / 128, NB), dim3(512), 0, stream, xp, Atile, Dp, out);
}

// Round 16
// 100.339 us; speedup vs baseline: 1.3615x; 1.0977x over previous
//
#include <hip/hip_runtime.h>
#include <stdint.h>

#define HW_  16384
#define CH   256
#define NB   8
#define EPSV 1e-5f

typedef float f32x4 __attribute__((ext_vector_type(4)));
typedef float f32x2 __attribute__((ext_vector_type(2)));
typedef short s16x8 __attribute__((ext_vector_type(8)));

__device__ __forceinline__ unsigned short f2bf(float f) {
    union { float f; uint32_t u; } v; v.f = f;
    uint32_t r = (v.u + 0x7FFFu + ((v.u >> 16) & 1u)) >> 16;  // RNE
    return (unsigned short)r;
}

// async global -> LDS. Global source address is PER-LANE; LDS dest is
// wave-uniform base + lane*16B (HW-appended).  [m104/m108]
__device__ __forceinline__ void glds16(const unsigned short* g, unsigned short* l) {
    __builtin_amdgcn_global_load_lds(
        (const __attribute__((address_space(1))) uint32_t*)g,
        (__attribute__((address_space(3))) uint32_t*)l,
        16, 0, 0);
}

// ---------------------------------------------------------------------------
// K1: per-(b,c) sum and sum-of-squares over H*W. 2048 blocks x 256 thr.
// ---------------------------------------------------------------------------
__global__ __launch_bounds__(256) void stats_kernel(const float* __restrict__ x,
                                                    float* __restrict__ sums,
                                                    float* __restrict__ sumsq) {
    const int bc  = blockIdx.x;
    const int tid = threadIdx.x;
    const float4* p = reinterpret_cast<const float4*>(x + (size_t)bc * HW_);
    float s = 0.f, q = 0.f;
#pragma unroll 4
    for (int i = tid; i < HW_ / 4; i += 256) {
        float4 v = p[i];
        s += v.x + v.y + v.z + v.w;
        q += v.x * v.x + v.y * v.y + v.z * v.z + v.w * v.w;
    }
    __shared__ float rs[256], rq[256];
    rs[tid] = s; rq[tid] = q;
    __syncthreads();
    for (int off = 128; off > 0; off >>= 1) {
        if (tid < off) { rs[tid] += rs[tid + off]; rq[tid] += rq[tid + off]; }
        __syncthreads();
    }
    if (tid == 0) { sums[bc] = rs[0]; sumsq[bc] = rq[0]; }
}

// ---------------------------------------------------------------------------
// K2: finalize stats, fold into A' + D'. A' written PRE-TILED in the gemm's
// LDS order: Atile[b][kb][g][m][8]  (kb = K-tile, g = k-octet, m = o).
// ---------------------------------------------------------------------------
__global__ __launch_bounds__(256) void prep_kernel(const float* __restrict__ sums,
                                                   const float* __restrict__ sumsq,
                                                   const float* __restrict__ params,
                                                   const float* __restrict__ W,
                                                   unsigned short* __restrict__ Atile,
                                                   float* __restrict__ Dp) {
    const int b   = blockIdx.x;
    const int tid = threadIdx.x;
    __shared__ float mu[CH], ri[CH], rs[CH], rq[CH];
    float s = sums[b * CH + tid];
    float q = sumsq[b * CH + tid];
    float m = s * (1.0f / HW_);
    float v = q * (1.0f / HW_) - m * m;
    mu[tid] = m;
    ri[tid] = rsqrtf(v + EPSV);
    rs[tid] = s; rq[tid] = q;
    __syncthreads();
    for (int off = 128; off > 0; off >>= 1) {
        if (tid < off) { rs[tid] += rs[tid + off]; rq[tid] += rq[tid + off]; }
        __syncthreads();
    }
    const float invN = 1.0f / ((float)CH * (float)HW_);
    const float mln  = rs[0] * invN;
    const float vln  = rq[0] * invN - mln * mln;
    const float rln  = rsqrtf(vln + EPSV);

    const int o = tid;
    const float gamma = params[b * 2 * CH + o];
    const float beta  = params[b * 2 * CH + CH + o];
    const float4* w1p = reinterpret_cast<const float4*>(W + (size_t)o * 2 * CH);
    const float4* w2p = reinterpret_cast<const float4*>(W + (size_t)o * 2 * CH + CH);
    unsigned short* ab = Atile + (size_t)b * (8 * 4 * 256 * 8);
    float t1 = 0.f, t2 = 0.f;
    for (int c4 = 0; c4 < CH / 4; ++c4) {
        float4 w1 = w1p[c4];
        float4 w2 = w2p[c4];
        float w1a[4] = {w1.x, w1.y, w1.z, w1.w};
        float w2a[4] = {w2.x, w2.y, w2.z, w2.w};
        const int c = c4 * 4;
        ushort4 pk;
        unsigned short* pka = (unsigned short*)&pk;
#pragma unroll
        for (int j = 0; j < 4; ++j) {
            float ric = ri[c + j];
            float a   = gamma * (w1a[j] * ric + w2a[j] * rln);
            pka[j] = f2bf(a);
            t1 += w1a[j] * ric * mu[c + j];
            t2 += w2a[j];
        }
        const int kb = c >> 5, g = (c >> 3) & 3, e0 = c & 4;
        *reinterpret_cast<ushort4*>(&ab[(size_t)(((kb * 4 + g) * 256 + o) * 8 + e0)]) = pk;
    }
    const float d = -(t1 + rln * mln * t2);
    Dp[b * CH + o] = gamma * d + beta;
}

// ---------------------------------------------------------------------------
// K3: batched MFMA GEMM — BN=64, 3 blocks/CU occupancy variant, SAFE barriers.
// out[b][m][n] = sum_c A'[b][m][c] * x[b][c][n] + D'
// BM=256, BN=64, BK=32. 512 thr = 8 waves, wave grid 4(m)x2(n), wave tile
// 64x32 (4x2 frags, acc=32 VGPR). launch_bounds(512,6) -> <=85 VGPR ->
// 6 waves/SIMD = 3 blocks/CU. Plain __syncthreads() (vmcnt(0)+lgkmcnt(0)):
// no issue-order assumptions (R15's counted-vmcnt assumed [glds,glds,x,x]
// issue order, which the compiler may legally permute -> NaN).
// Per K-step: barrier -> DMA As(kb+1) -> load x(kb+2) -> compute(kb)
//           -> ds_write Xs(kb+1) from regs loaded at kb-1.
// ---------------------------------------------------------------------------
__global__ __launch_bounds__(512, 6) void gemm_kernel(const float* __restrict__ x,
                                                      const unsigned short* __restrict__ Atile,
                                                      const float* __restrict__ Dp,
                                                      float* __restrict__ out) {
    __shared__ unsigned short As[2][4 * 256 * 8];  // [buf][g][m][8]   16 KB each
    __shared__ unsigned short Xs[2][4 * 64 * 8];   // [buf][g][n_p][8]  4 KB each

    const int b   = blockIdx.y;
    const int n0  = blockIdx.x * 64;
    const int t   = threadIdx.x;
    const int w   = t >> 6;
    const int l   = t & 63;
    const int wm  = w >> 1;        // 0..3 (64-row m slice)
    const int wn  = w & 1;         // 0..1 (32-wide n half)
    const int lhi = l >> 4;        // 0..3 (k-group)
    const int llo = l & 15;

    // acc init = bias D' (MFMA C-operand): D row = wm*64+fm*16+lhi*4+r
    f32x4 acc[4][2];
    const float* dpb = Dp + b * CH;
#pragma unroll
    for (int fm = 0; fm < 4; ++fm) {
        f32x4 d = *reinterpret_cast<const f32x4*>(dpb + wm * 64 + fm * 16 + lhi * 4);
        acc[fm][0] = d; acc[fm][1] = d;
    }

    const unsigned short* apb = Atile + (size_t)b * (8 * 4 * 256 * 8);
    uint32_t* Xs32 = reinterpret_cast<uint32_t*>(&Xs[0][0]);

    // ---- As DMA mapping: wave w issues instrs i=2w,2w+1; i -> (g=i&3, q=i>>2)
    const int i0 = 2 * w,      i1 = 2 * w + 1;
    const int g0 = i0 & 3,     q0 = i0 >> 2;
    const int g1 = i1 & 3,     q1 = i1 >> 2;
    const unsigned short* aglob0 = apb + (size_t)(g0 * 256 + q0 * 64 + l) * 8;
    const unsigned short* aglob1 = apb + (size_t)(g1 * 256 + q1 * 64 + l) * 8;
    unsigned short* alds0 = &As[0][g0 * 2048 + q0 * 512];  // + l*16B by HW
    unsigned short* alds1 = &As[0][g1 * 2048 + q1 * 512];

    // ---- Xs staging mapping: thread -> k-pair kp (0..15), n-pair n2
    const int kp = t >> 5;              // half-wave shares kp -> 256B row segs
    const int n2 = (t & 31) * 2;        // 2 consecutive n per thread
    const int xg = kp >> 2;             // Xs g
    const int xh = kp & 3;              // u32 slot within octet
    const float* xlane = x + (size_t)b * CH * HW_ + (size_t)(2 * kp) * HW_ + n0 + n2;

    // read-side swizzled n per fn (n in 0..63)
    int npr[2];
#pragma unroll
    for (int fn = 0; fn < 2; ++fn) {
        const int nr = wn * 32 + fn * 16 + llo;
        npr[fn] = nr ^ ((nr >> 3) & 7);
    }

    // ---- prologue: DMA As(0), load x tiles 0 and 1, stage Xs[0]
    glds16(aglob0, alds0);
    glds16(aglob1, alds1);
    f32x2 xa[2], xb[2];   // [buf] rows 2kp / 2kp+1, 2 n each
    xa[0] = *reinterpret_cast<const f32x2*>(xlane);
    xb[0] = *reinterpret_cast<const f32x2*>(xlane + HW_);
    xa[1] = *reinterpret_cast<const f32x2*>(xlane + (size_t)32 * HW_);
    xb[1] = *reinterpret_cast<const f32x2*>(xlane + (size_t)32 * HW_ + HW_);
#pragma unroll
    for (int j = 0; j < 2; ++j) {
        const int n  = n2 + j;
        const int np = n ^ ((n >> 3) & 7);
        Xs32[xg * 256 + np * 4 + xh] =
            (uint32_t)f2bf(xa[0][j]) | ((uint32_t)f2bf(xb[0][j]) << 16);
    }

#pragma unroll
    for (int kb = 0; kb < 8; ++kb) {
        __syncthreads();   // vmcnt(0)+lgkmcnt(0): DMA(kb)+stage(kb) complete
        const int cur = kb & 1, nxt = cur ^ 1;

        if (kb < 7) {
            glds16(aglob0 + (kb + 1) * 8192, alds0 + nxt * 8192);
            glds16(aglob1 + (kb + 1) * 8192, alds1 + nxt * 8192);
        }
        if (kb < 6) {
            const float* xp = xlane + (size_t)(kb + 2) * 32 * HW_;
            xa[cur] = *reinterpret_cast<const f32x2*>(xp);
            xb[cur] = *reinterpret_cast<const f32x2*>(xp + HW_);
        }

        // compute(kb)
        s16x8 af[4];
#pragma unroll
        for (int fm = 0; fm < 4; ++fm)
            af[fm] = *reinterpret_cast<const s16x8*>(&As[cur][lhi * 2048 + (wm * 64 + fm * 16 + llo) * 8]);
#pragma unroll
        for (int fn = 0; fn < 2; ++fn) {
            s16x8 bfr = *reinterpret_cast<const s16x8*>(&Xs[cur][lhi * 512 + npr[fn] * 8]);
#pragma unroll
            for (int fm = 0; fm < 4; ++fm)
                acc[fm][fn] = __builtin_amdgcn_mfma_f32_16x16x32_bf16(af[fm], bfr, acc[fm][fn], 0, 0, 0);
        }

        // stage Xs(kb+1) AFTER compute from regs loaded one phase earlier.
        // Buffer stride = 1024 u32 (4KB).
        if (kb < 7) {
#pragma unroll
            for (int j = 0; j < 2; ++j) {
                const int n  = n2 + j;
                const int np = n ^ ((n >> 3) & 7);
                Xs32[nxt * 1024 + xg * 256 + np * 4 + xh] =
                    (uint32_t)f2bf(xa[nxt][j]) | ((uint32_t)f2bf(xb[nxt][j]) << 16);
            }
        }
    }

    // epilogue: bias already folded into acc
#pragma unroll
    for (int fm = 0; fm < 4; ++fm) {
        const int m = wm * 64 + fm * 16 + lhi * 4;
        float* obase = out + (size_t)(b * CH + m) * HW_ + n0 + wn * 32 + llo;
#pragma unroll
        for (int fn = 0; fn < 2; ++fn) {
#pragma unroll
            for (int r = 0; r < 4; ++r)
                obase[(size_t)r * HW_ + fn * 16] = acc[fm][fn][r];
        }
    }
}

// ---------------------------------------------------------------------------
extern "C" void kernel_launch(void* const* d_in, const int* in_sizes, int n_in,
                              void* d_out, int out_size, void* d_ws, size_t ws_size,
                              hipStream_t stream) {
    const float* x      = (const float*)d_in[0];
    const float* params = (const float*)d_in[1];
    const float* W      = (const float*)d_in[2];
    float* out = (float*)d_out;
    float* ws  = (float*)d_ws;

    float* sums  = ws;                 // 2048 f32
    float* sumsq = ws + 2048;          // 2048 f32
    float* Dp    = ws + 4096;          // 2048 f32
    unsigned short* Atile = (unsigned short*)(ws + 6144);  // 8*65536 shorts = 1 MB

    hipLaunchKernelGGL(stats_kernel, dim3(NB * CH), dim3(256), 0, stream, x, sums, sumsq);
    hipLaunchKernelGGL(prep_kernel,  dim3(NB),      dim3(256), 0, stream, sums, sumsq, params, W, Atile, Dp);
    hipLaunchKernelGGL(gemm_kernel,  dim3(HW_ / 64, NB), dim3(512), 0, stream, x, Atile, Dp, out);
}

// Round 17
// 96.029 us; speedup vs baseline: 1.4226x; 1.0449x over previous
//
#include <hip/hip_runtime.h>
#include <stdint.h>

#define HW_  16384
#define CH   256
#define NB   8
#define EPSV 1e-5f

typedef float f32x4 __attribute__((ext_vector_type(4)));
typedef short s16x8 __attribute__((ext_vector_type(8)));

__device__ __forceinline__ unsigned short f2bf(float f) {
    union { float f; uint32_t u; } v; v.f = f;
    uint32_t r = (v.u + 0x7FFFu + ((v.u >> 16) & 1u)) >> 16;  // RNE
    return (unsigned short)r;
}

// async global -> LDS. Global source address is PER-LANE; LDS dest is
// wave-uniform base + lane*16B (HW-appended).  [m104/m108]
__device__ __forceinline__ void glds16(const unsigned short* g, unsigned short* l) {
    __builtin_amdgcn_global_load_lds(
        (const __attribute__((address_space(1))) uint32_t*)g,
        (__attribute__((address_space(3))) uint32_t*)l,
        16, 0, 0);
}

// ---------------------------------------------------------------------------
// K1: per-(b,c) sum and sum-of-squares over H*W. 2048 blocks x 256 thr.
// ---------------------------------------------------------------------------
__global__ __launch_bounds__(256) void stats_kernel(const float* __restrict__ x,
                                                    float* __restrict__ sums,
                                                    float* __restrict__ sumsq) {
    const int bc  = blockIdx.x;
    const int tid = threadIdx.x;
    const float4* p = reinterpret_cast<const float4*>(x + (size_t)bc * HW_);
    float s = 0.f, q = 0.f;
#pragma unroll 4
    for (int i = tid; i < HW_ / 4; i += 256) {
        float4 v = p[i];
        s += v.x + v.y + v.z + v.w;
        q += v.x * v.x + v.y * v.y + v.z * v.z + v.w * v.w;
    }
    __shared__ float rs[256], rq[256];
    rs[tid] = s; rq[tid] = q;
    __syncthreads();
    for (int off = 128; off > 0; off >>= 1) {
        if (tid < off) { rs[tid] += rs[tid + off]; rq[tid] += rq[tid + off]; }
        __syncthreads();
    }
    if (tid == 0) { sums[bc] = rs[0]; sumsq[bc] = rq[0]; }
}

// ---------------------------------------------------------------------------
// K2: finalize stats, fold into A' + D'. A' written PRE-TILED in the gemm's
// LDS order: Atile[b][kb][g][m][8]  (kb = K-tile, g = k-octet, m = o).
// ---------------------------------------------------------------------------
__global__ __launch_bounds__(256) void prep_kernel(const float* __restrict__ sums,
                                                   const float* __restrict__ sumsq,
                                                   const float* __restrict__ params,
                                                   const float* __restrict__ W,
                                                   unsigned short* __restrict__ Atile,
                                                   float* __restrict__ Dp) {
    const int b   = blockIdx.x;
    const int tid = threadIdx.x;
    __shared__ float mu[CH], ri[CH], rs[CH], rq[CH];
    float s = sums[b * CH + tid];
    float q = sumsq[b * CH + tid];
    float m = s * (1.0f / HW_);
    float v = q * (1.0f / HW_) - m * m;
    mu[tid] = m;
    ri[tid] = rsqrtf(v + EPSV);
    rs[tid] = s; rq[tid] = q;
    __syncthreads();
    for (int off = 128; off > 0; off >>= 1) {
        if (tid < off) { rs[tid] += rs[tid + off]; rq[tid] += rq[tid + off]; }
        __syncthreads();
    }
    const float invN = 1.0f / ((float)CH * (float)HW_);
    const float mln  = rs[0] * invN;
    const float vln  = rq[0] * invN - mln * mln;
    const float rln  = rsqrtf(vln + EPSV);

    const int o = tid;
    const float gamma = params[b * 2 * CH + o];
    const float beta  = params[b * 2 * CH + CH + o];
    const float4* w1p = reinterpret_cast<const float4*>(W + (size_t)o * 2 * CH);
    const float4* w2p = reinterpret_cast<const float4*>(W + (size_t)o * 2 * CH + CH);
    unsigned short* ab = Atile + (size_t)b * (8 * 4 * 256 * 8);
    float t1 = 0.f, t2 = 0.f;
    for (int c4 = 0; c4 < CH / 4; ++c4) {
        float4 w1 = w1p[c4];
        float4 w2 = w2p[c4];
        float w1a[4] = {w1.x, w1.y, w1.z, w1.w};
        float w2a[4] = {w2.x, w2.y, w2.z, w2.w};
        const int c = c4 * 4;
        ushort4 pk;
        unsigned short* pka = (unsigned short*)&pk;
#pragma unroll
        for (int j = 0; j < 4; ++j) {
            float ric = ri[c + j];
            float a   = gamma * (w1a[j] * ric + w2a[j] * rln);
            pka[j] = f2bf(a);
            t1 += w1a[j] * ric * mu[c + j];
            t2 += w2a[j];
        }
        const int kb = c >> 5, g = (c >> 3) & 3, e0 = c & 4;
        *reinterpret_cast<ushort4*>(&ab[(size_t)(((kb * 4 + g) * 256 + o) * 8 + e0)]) = pk;
    }
    const float d = -(t1 + rln * mln * t2);
    Dp[b * CH + o] = gamma * d + beta;
}

// ---------------------------------------------------------------------------
// K3: batched MFMA GEMM (R10 structure; safe barriers; L3-warmth b-reversal).
// out[b][m][n] = sum_c A'[b][m][c] * x[b][c][n] + D'
// BM=256, BN=128, BK=32. 512 thr = 8 waves, wave 64x64 (4x4 frags 16x16x32).
// b = 7 - blockIdx.y: stats reads x with b ascending, so high-b lines are the
// warmest in L3 at gemm launch; earliest gemm blocks read them first.
// Per K-step: __syncthreads (full drain; no issue-order assumptions - R15
// showed counted-vmcnt is codegen-fragile) -> DMA As(kb+1) (lane-consecutive
// 16B from pre-tiled Atile) -> load x(kb+2) -> compute(kb) -> stage Xs(kb+1).
// ---------------------------------------------------------------------------
__global__ __launch_bounds__(512, 4) void gemm_kernel(const float* __restrict__ x,
                                                      const unsigned short* __restrict__ Atile,
                                                      const float* __restrict__ Dp,
                                                      float* __restrict__ out) {
    __shared__ unsigned short As[2][4 * 256 * 8];  // [buf][g][m][8]   16 KB each
    __shared__ unsigned short Xs[2][4 * 128 * 8];  // [buf][g][n_p][8]  8 KB each

    const int b   = NB - 1 - blockIdx.y;   // L3-warmth: warmest batch first
    const int n0  = blockIdx.x * 128;
    const int t   = threadIdx.x;
    const int w   = t >> 6;
    const int l   = t & 63;
    const int wm  = w >> 1;        // 0..3
    const int wn  = w & 1;         // 0..1
    const int lhi = l >> 4;        // 0..3 (k-group)
    const int llo = l & 15;

    // acc init = bias D' (MFMA C-operand)
    f32x4 acc[4][4];
    const float* dpb = Dp + b * CH;
#pragma unroll
    for (int fm = 0; fm < 4; ++fm) {
        f32x4 d = *reinterpret_cast<const f32x4*>(dpb + wm * 64 + fm * 16 + lhi * 4);
#pragma unroll
        for (int fn = 0; fn < 4; ++fn) acc[fm][fn] = d;
    }

    const size_t xbase = (size_t)b * CH * HW_ + n0;
    const unsigned short* apb = Atile + (size_t)b * (8 * 4 * 256 * 8);
    uint32_t* Xs32 = reinterpret_cast<uint32_t*>(&Xs[0][0]);

    // ---- As DMA mapping: wave w issues instrs i=2w,2w+1; i -> (g=i&3, q=i>>2)
    // global: per-lane consecutive 16B within [kb][g][q*64..q*64+63][8]
    const int i0 = 2 * w,      i1 = 2 * w + 1;
    const int g0 = i0 & 3,     q0 = i0 >> 2;
    const int g1 = i1 & 3,     q1 = i1 >> 2;
    const unsigned short* aglob0 = apb + (size_t)(g0 * 256 + q0 * 64 + l) * 8;
    const unsigned short* aglob1 = apb + (size_t)(g1 * 256 + q1 * 64 + l) * 8;
    unsigned short* alds0 = &As[0][g0 * 2048 + q0 * 512];  // + l*16B by HW
    unsigned short* alds1 = &As[0][g1 * 2048 + q1 * 512];

    // ---- Xs staging mapping
    const int kp = t >> 5;              // k-pair 0..15 (rows 2kp, 2kp+1)
    const int nq = t & 31;              // n-quad (half-wave = 512B row segment)
    const int xg = kp >> 2;             // Xs g
    const int xh = kp & 3;              // u32 slot within octet
    const float* xlane = x + xbase + (size_t)(2 * kp) * HW_ + nq * 4;

    // read-side swizzled n per fn
    int npr[4];
#pragma unroll
    for (int fn = 0; fn < 4; ++fn) {
        const int nr = wn * 64 + fn * 16 + llo;
        npr[fn] = nr ^ ((nr >> 3) & 7);
    }

    // ---- prologue: DMA As(0), load x tiles 0 and 1, stage Xs[0]
    glds16(aglob0, alds0);
    glds16(aglob1, alds1);
    f32x4 xa[2], xb[2];
    xa[0] = *reinterpret_cast<const f32x4*>(xlane);
    xb[0] = *reinterpret_cast<const f32x4*>(xlane + HW_);
    xa[1] = *reinterpret_cast<const f32x4*>(xlane + (size_t)32 * HW_);
    xb[1] = *reinterpret_cast<const f32x4*>(xlane + (size_t)32 * HW_ + HW_);
#pragma unroll
    for (int j = 0; j < 4; ++j) {
        const int n  = nq * 4 + j;
        const int np = n ^ ((n >> 3) & 7);
        Xs32[xg * 512 + np * 4 + xh] =
            (uint32_t)f2bf(xa[0][j]) | ((uint32_t)f2bf(xb[0][j]) << 16);
    }

#pragma unroll
    for (int kb = 0; kb < 8; ++kb) {
        __syncthreads();   // full drain: DMA(kb) + stage(kb) complete, safe
        const int cur = kb & 1, nxt = cur ^ 1;

        if (kb < 7) {
            // DMA As(kb+1): lane-consecutive 16B -> 1KB coalesced per instr
            glds16(aglob0 + (kb + 1) * 8192, alds0 + nxt * 8192);
            glds16(aglob1 + (kb + 1) * 8192, alds1 + nxt * 8192);
        }
        if (kb < 6) {
            const float* xp = xlane + (size_t)(kb + 2) * 32 * HW_;
            xa[cur] = *reinterpret_cast<const f32x4*>(xp);
            xb[cur] = *reinterpret_cast<const f32x4*>(xp + HW_);
        }

        // compute(kb) from cur buffers
        s16x8 af[4];
#pragma unroll
        for (int fm = 0; fm < 4; ++fm)
            af[fm] = *reinterpret_cast<const s16x8*>(&As[cur][lhi * 2048 + (wm * 64 + fm * 16 + llo) * 8]);
#pragma unroll
        for (int fn = 0; fn < 4; ++fn) {
            s16x8 bfr = *reinterpret_cast<const s16x8*>(&Xs[cur][lhi * 1024 + npr[fn] * 8]);
#pragma unroll
            for (int fm = 0; fm < 4; ++fm)
                acc[fm][fn] = __builtin_amdgcn_mfma_f32_16x16x32_bf16(af[fm], bfr, acc[fm][fn], 0, 0, 0);
        }

        // stage Xs(kb+1) AFTER compute from regs loaded one phase earlier
        if (kb < 7) {
#pragma unroll
            for (int j = 0; j < 4; ++j) {
                const int n  = nq * 4 + j;
                const int np = n ^ ((n >> 3) & 7);
                Xs32[nxt * 2048 + xg * 512 + np * 4 + xh] =
                    (uint32_t)f2bf(xa[nxt][j]) | ((uint32_t)f2bf(xb[nxt][j]) << 16);
            }
        }
    }

    // epilogue: bias already folded into acc
#pragma unroll
    for (int fm = 0; fm < 4; ++fm) {
        const int m = wm * 64 + fm * 16 + lhi * 4;
        float* obase = out + (size_t)(b * CH + m) * HW_ + n0 + wn * 64 + llo;
#pragma unroll
        for (int fn = 0; fn < 4; ++fn) {
#pragma unroll
            for (int r = 0; r < 4; ++r)
                obase[(size_t)r * HW_ + fn * 16] = acc[fm][fn][r];
        }
    }
}

// ---------------------------------------------------------------------------
extern "C" void kernel_launch(void* const* d_in, const int* in_sizes, int n_in,
                              void* d_out, int out_size, void* d_ws, size_t ws_size,
                              hipStream_t stream) {
    const float* x      = (const float*)d_in[0];
    const float* params = (const float*)d_in[1];
    const float* W      = (const float*)d_in[2];
    float* out = (float*)d_out;
    float* ws  = (float*)d_ws;

    float* sums  = ws;                 // 2048 f32
    float* sumsq = ws + 2048;          // 2048 f32
    float* Dp    = ws + 4096;          // 2048 f32
    unsigned short* Atile = (unsigned short*)(ws + 6144);  // 8*65536 shorts = 1 MB

    hipLaunchKernelGGL(stats_kernel, dim3(NB * CH), dim3(256), 0, stream, x, sums, sumsq);
    hipLaunchKernelGGL(prep_kernel,  dim3(NB),      dim3(256), 0, stream, sums, sumsq, params, W, Atile, Dp);
    hipLaunchKernelGGL(gemm_kernel,  dim3(HW_ / 128, NB), dim3(512), 0, stream, x, Atile, Dp, out);
}